// Round 1
// baseline (1911.390 us; speedup 1.0000x reference)
//
#include <hip/hip_runtime.h>

constexpr int Bn  = 4096;
constexpr int OBS = 390;
constexpr int ACTN = 20;
constexpr int IN  = 410;   // OBS + ACTN
constexpr int E   = 8;
constexpr int H1  = 1024;
constexpr int H2  = 512;
constexpr int D   = 256;

// ---------------- concat: x = [state_feat | act] ----------------
__global__ void concat_kernel(const float* __restrict__ sf,
                              const float* __restrict__ ac,
                              float* __restrict__ x) {
    int idx = blockIdx.x * blockDim.x + threadIdx.x;
    if (idx >= Bn * IN) return;
    int b = idx / IN;
    int k = idx - b * IN;
    x[idx] = (k < OBS) ? sf[b * OBS + k] : ac[b * ACTN + (k - OBS)];
}

// ---------------- query = tanh(emb[task_id]) ----------------
__global__ void query_kernel(const float* __restrict__ emb,
                             const int* __restrict__ task_id,
                             float* __restrict__ query) {
    int idx = blockIdx.x * blockDim.x + threadIdx.x;  // B*D threads
    int b = idx >> 8;          // /256
    int d = idx & 255;
    query[idx] = tanhf(emb[task_id[b] * D + d]);
}

// ---------------- generic fp32 tiled GEMM ----------------
// C[M,N] = act(A[M,K] @ W[K,N] + bias[N]); optional group (blockIdx.z) strides.
// Requires: M%64==0, N%64==0, ldw%4==0, ldc%4==0. K may be ragged.
template <int ACTF>
__global__ __launch_bounds__(256) void gemm_f32(
    const float* __restrict__ A, const float* __restrict__ W,
    const float* __restrict__ bias, float* __restrict__ C,
    int M, int N, int K, int lda, int ldw, int ldc,
    long long gsA, long long gsW, long long gsB, long long gsC)
{
    int g = blockIdx.z;
    A    += (long long)g * gsA;
    W    += (long long)g * gsW;
    bias += (long long)g * gsB;
    C    += (long long)g * gsC;

    __shared__ float As[16][68];   // [k][m], row stride 68 floats (16B-aligned rows)
    __shared__ float Ws[16][68];   // [k][n]

    const int t  = threadIdx.x;
    const int tx = t & 15;
    const int ty = t >> 4;
    const int gm = blockIdx.y * 64;
    const int gn = blockIdx.x * 64;

    float acc[4][4] = {};

    for (int k0 = 0; k0 < K; k0 += 16) {
        // A tile: thread t loads row m = t>>2, k-quad j0 = (t&3)*4 (scalar, K-guarded)
        {
            int m  = t >> 2;
            int j0 = (t & 3) * 4;
            const float* Ap = A + (long long)(gm + m) * lda + k0 + j0;
#pragma unroll
            for (int j = 0; j < 4; ++j)
                As[j0 + j][m] = (k0 + j0 + j < K) ? Ap[j] : 0.f;
        }
        // W tile: thread t loads k-row kk = t>>4, n-quad n0 = (t&15)*4 (float4)
        {
            int kk = t >> 4;
            int n0 = tx * 4;
            float4 w4 = make_float4(0.f, 0.f, 0.f, 0.f);
            if (k0 + kk < K)
                w4 = *(const float4*)(W + (long long)(k0 + kk) * ldw + gn + n0);
            *(float4*)&Ws[kk][n0] = w4;
        }
        __syncthreads();

#pragma unroll
        for (int kk = 0; kk < 16; ++kk) {
            float4 a4 = *(const float4*)&As[kk][ty * 4];
            float4 b4 = *(const float4*)&Ws[kk][tx * 4];
            acc[0][0] += a4.x * b4.x; acc[0][1] += a4.x * b4.y; acc[0][2] += a4.x * b4.z; acc[0][3] += a4.x * b4.w;
            acc[1][0] += a4.y * b4.x; acc[1][1] += a4.y * b4.y; acc[1][2] += a4.y * b4.z; acc[1][3] += a4.y * b4.w;
            acc[2][0] += a4.z * b4.x; acc[2][1] += a4.z * b4.y; acc[2][2] += a4.z * b4.z; acc[2][3] += a4.z * b4.w;
            acc[3][0] += a4.w * b4.x; acc[3][1] += a4.w * b4.y; acc[3][2] += a4.w * b4.z; acc[3][3] += a4.w * b4.w;
        }
        __syncthreads();
    }

    float4 bb = *(const float4*)&bias[gn + tx * 4];
#pragma unroll
    for (int i = 0; i < 4; ++i) {
        int row = gm + ty * 4 + i;
        float4 c;
        c.x = acc[i][0] + bb.x;
        c.y = acc[i][1] + bb.y;
        c.z = acc[i][2] + bb.z;
        c.w = acc[i][3] + bb.w;
        if (ACTF == 1) {
            c.x = fmaxf(c.x, 0.f); c.y = fmaxf(c.y, 0.f);
            c.z = fmaxf(c.z, 0.f); c.w = fmaxf(c.w, 0.f);
        }
        *(float4*)&C[(long long)row * ldc + gn + tx * 4] = c;
    }
}

// ---------------- attention: scores -> softmax -> weighted sum + loss partials ----------------
// one wave per row b; 4 rows per 256-thread block
__global__ __launch_bounds__(256) void attn_kernel(
    const float* __restrict__ query, const float* __restrict__ keys,
    const float* __restrict__ vals, float* __restrict__ tower_in,
    float* __restrict__ loss_partial)
{
    int wv   = threadIdx.x >> 6;
    int lane = threadIdx.x & 63;
    int b    = blockIdx.x * 4 + wv;
    int d0   = lane * 4;

    const float4 q4 = *(const float4*)&query[(long long)b * D + d0];

    float s[E];
#pragma unroll
    for (int e = 0; e < E; ++e) {
        const float4 k4 = *(const float4*)&keys[((long long)e * Bn + b) * D + d0];
        float p = q4.x * k4.x + q4.y * k4.y + q4.z * k4.z + q4.w * k4.w;
#pragma unroll
        for (int off = 32; off > 0; off >>= 1) p += __shfl_xor(p, off, 64);
        s[e] = p;
    }

    float m = s[0];
#pragma unroll
    for (int e = 1; e < E; ++e) m = fmaxf(m, s[e]);
    float w[E];
    float sum = 0.f;
#pragma unroll
    for (int e = 0; e < E; ++e) { w[e] = expf(s[e] - m); sum += w[e]; }
    float inv = 1.f / sum;

    float4 acc = make_float4(0.f, 0.f, 0.f, 0.f);
    float lb = 0.f;
#pragma unroll
    for (int e = 0; e < E; ++e) {
        float we = w[e] * inv;
        const float4 v4 = *(const float4*)&vals[((long long)e * Bn + b) * D + d0];
        acc.x += we * v4.x; acc.y += we * v4.y;
        acc.z += we * v4.z; acc.w += we * v4.w;
        lb += fminf(fmaxf(logf(we + 1e-10f), -6.f), 0.f);
    }
    *(float4*)&tower_in[(long long)b * D + d0] = acc;

    __shared__ float sm[4];
    if (lane == 0) sm[wv] = lb;   // lb identical across lanes (butterfly broadcast)
    __syncthreads();
    if (threadIdx.x == 0)
        loss_partial[blockIdx.x] = sm[0] + sm[1] + sm[2] + sm[3];
}

// ---------------- q = t2 @ tW3 + tb3 ----------------
__global__ __launch_bounds__(256) void qdot_kernel(
    const float* __restrict__ t2, const float* __restrict__ tW3,
    const float* __restrict__ tb3, float* __restrict__ out)
{
    int wv   = threadIdx.x >> 6;
    int lane = threadIdx.x & 63;
    int b    = blockIdx.x * 4 + wv;
    int d0   = lane * 4;
    float4 h4 = *(const float4*)&t2[(long long)b * D + d0];
    float4 w4 = *(const float4*)&tW3[d0];
    float p = h4.x * w4.x + h4.y * w4.y + h4.z * w4.z + h4.w * w4.w;
#pragma unroll
    for (int off = 32; off > 0; off >>= 1) p += __shfl_xor(p, off, 64);
    if (lane == 0) out[b] = p + tb3[0];
}

// ---------------- final loss reduce ----------------
__global__ __launch_bounds__(256) void loss_reduce(const float* __restrict__ partial,
                                                   float* __restrict__ out) {
    float s = 0.f;
    for (int i = threadIdx.x; i < Bn / 4; i += 256) s += partial[i];
#pragma unroll
    for (int off = 32; off > 0; off >>= 1) s += __shfl_xor(s, off, 64);
    __shared__ float sm[4];
    if ((threadIdx.x & 63) == 0) sm[threadIdx.x >> 6] = s;
    __syncthreads();
    if (threadIdx.x == 0) out[0] = (-0.3f / Bn) * (sm[0] + sm[1] + sm[2] + sm[3]);
}

extern "C" void kernel_launch(void* const* d_in, const int* in_sizes, int n_in,
                              void* d_out, int out_size, void* d_ws, size_t ws_size,
                              hipStream_t stream) {
    const float* state_feat = (const float*)d_in[0];
    const float* act        = (const float*)d_in[1];
    const int*   task_id    = (const int*)d_in[2];
    const float* rep_W1     = (const float*)d_in[3];
    const float* rep_b1     = (const float*)d_in[4];
    const float* rep_W2     = (const float*)d_in[5];
    const float* rep_b2     = (const float*)d_in[6];
    const float* emb        = (const float*)d_in[7];
    const float* kW1 = (const float*)d_in[8];
    const float* kb1 = (const float*)d_in[9];
    const float* kW2 = (const float*)d_in[10];
    const float* kb2 = (const float*)d_in[11];
    const float* vW1 = (const float*)d_in[12];
    const float* vb1 = (const float*)d_in[13];
    const float* vW2 = (const float*)d_in[14];
    const float* vb2 = (const float*)d_in[15];
    const float* tW1 = (const float*)d_in[16];
    const float* tb1 = (const float*)d_in[17];
    const float* tW2 = (const float*)d_in[18];
    const float* tb2 = (const float*)d_in[19];
    const float* tW3 = (const float*)d_in[20];
    const float* tb3 = (const float*)d_in[21];
    float* out = (float*)d_out;

    float* ws = (float*)d_ws;
    float* x        = ws;                        // Bn*IN
    float* h1       = x + (size_t)Bn * IN;       // Bn*H1
    float* rep      = h1 + (size_t)Bn * H1;      // Bn*H1
    float* keys     = rep + (size_t)Bn * H1;     // E*Bn*D
    float* vals     = keys + (size_t)E * Bn * D; // E*Bn*D
    float* query    = vals + (size_t)E * Bn * D; // Bn*D
    float* tower_in = query + (size_t)Bn * D;    // Bn*D
    float* lossp    = tower_in + (size_t)Bn * D; // Bn/4
    float* hbuf     = lossp + 1024;              // Bn*H2 (serial) or E*Bn*H2 (batched)
    float* t1 = h1;   // alias: h1 dead after rep-GEMM
    float* t2 = x;    // alias: x dead after first GEMM

    size_t base_floats = (size_t)Bn * IN + 2ull * Bn * H1 + 2ull * E * Bn * D
                       + 2ull * Bn * D + 1024;
    bool batched = ws_size >= (base_floats + (size_t)E * Bn * H2) * sizeof(float);

    // 1. concat
    {
        int total = Bn * IN;
        concat_kernel<<<(total + 255) / 256, 256, 0, stream>>>(state_feat, act, x);
    }
    // 2. h1 = ReLU(x @ rep_W1 + rep_b1)
    gemm_f32<1><<<dim3(H1 / 64, Bn / 64, 1), 256, 0, stream>>>(
        x, rep_W1, rep_b1, h1, Bn, H1, IN, IN, H1, H1, 0, 0, 0, 0);
    // 3. rep = h1 @ rep_W2 + rep_b2 (no activation)
    gemm_f32<0><<<dim3(H1 / 64, Bn / 64, 1), 256, 0, stream>>>(
        h1, rep_W2, rep_b2, rep, Bn, H1, H1, H1, H1, H1, 0, 0, 0, 0);
    // 4. query
    query_kernel<<<(Bn * D) / 256, 256, 0, stream>>>(emb, task_id, query);

    // 5. expert K/V MLPs
    if (batched) {
        gemm_f32<1><<<dim3(H2 / 64, Bn / 64, E), 256, 0, stream>>>(
            rep, kW1, kb1, hbuf, Bn, H2, H1, H1, H2, H2,
            0, (long long)H1 * H2, H2, (long long)Bn * H2);
        gemm_f32<0><<<dim3(D / 64, Bn / 64, E), 256, 0, stream>>>(
            hbuf, kW2, kb2, keys, Bn, D, H2, H2, D, D,
            (long long)Bn * H2, (long long)H2 * D, D, (long long)Bn * D);
        gemm_f32<1><<<dim3(H2 / 64, Bn / 64, E), 256, 0, stream>>>(
            rep, vW1, vb1, hbuf, Bn, H2, H1, H1, H2, H2,
            0, (long long)H1 * H2, H2, (long long)Bn * H2);
        gemm_f32<0><<<dim3(D / 64, Bn / 64, E), 256, 0, stream>>>(
            hbuf, vW2, vb2, vals, Bn, D, H2, H2, D, D,
            (long long)Bn * H2, (long long)H2 * D, D, (long long)Bn * D);
    } else {
        for (int e = 0; e < E; ++e) {
            gemm_f32<1><<<dim3(H2 / 64, Bn / 64, 1), 256, 0, stream>>>(
                rep, kW1 + (size_t)e * H1 * H2, kb1 + e * H2, hbuf,
                Bn, H2, H1, H1, H2, H2, 0, 0, 0, 0);
            gemm_f32<0><<<dim3(D / 64, Bn / 64, 1), 256, 0, stream>>>(
                hbuf, kW2 + (size_t)e * H2 * D, kb2 + e * D, keys + (size_t)e * Bn * D,
                Bn, D, H2, H2, D, D, 0, 0, 0, 0);
            gemm_f32<1><<<dim3(H2 / 64, Bn / 64, 1), 256, 0, stream>>>(
                rep, vW1 + (size_t)e * H1 * H2, vb1 + e * H2, hbuf,
                Bn, H2, H1, H1, H2, H2, 0, 0, 0, 0);
            gemm_f32<0><<<dim3(D / 64, Bn / 64, 1), 256, 0, stream>>>(
                hbuf, vW2 + (size_t)e * H2 * D, vb2 + e * D, vals + (size_t)e * Bn * D,
                Bn, D, H2, H2, D, D, 0, 0, 0, 0);
        }
    }

    // 6. attention + softmax + loss partials
    attn_kernel<<<Bn / 4, 256, 0, stream>>>(query, keys, vals, tower_in, lossp);

    // 7-8. tower
    gemm_f32<1><<<dim3(D / 64, Bn / 64, 1), 256, 0, stream>>>(
        tower_in, tW1, tb1, t1, Bn, D, D, D, D, D, 0, 0, 0, 0);
    gemm_f32<1><<<dim3(D / 64, Bn / 64, 1), 256, 0, stream>>>(
        t1, tW2, tb2, t2, Bn, D, D, D, D, D, 0, 0, 0, 0);

    // 9. q
    qdot_kernel<<<Bn / 4, 256, 0, stream>>>(t2, tW3, tb3, out);
    // 10. expert loss
    loss_reduce<<<1, 256, 0, stream>>>(lossp, out + Bn);
}

// Round 2
// 260.535 us; speedup vs baseline: 7.3364x; 7.3364x over previous
//
#include <hip/hip_runtime.h>

constexpr int Bn   = 4096;
constexpr int OBS  = 390;
constexpr int ACTN = 20;
constexpr int IN   = 410;   // OBS + ACTN
constexpr int KPAD = 416;   // IN padded to multiple of 32
constexpr int E    = 8;
constexpr int H1   = 1024;
constexpr int H2   = 512;
constexpr int D    = 256;

typedef __bf16 bf16x8 __attribute__((ext_vector_type(8)));
typedef float  f32x4  __attribute__((ext_vector_type(4)));

__device__ __forceinline__ unsigned short f2bf(float f) {
    unsigned int u = __float_as_uint(f);
    unsigned int r = u + 0x7fffu + ((u >> 16) & 1u);   // RNE
    return (unsigned short)(r >> 16);
}
__device__ __forceinline__ float bf2f(unsigned short h) {
    return __uint_as_float(((unsigned int)h) << 16);
}
__device__ __forceinline__ void gload16(void* lds_dst, const void* g_src) {
    __builtin_amdgcn_global_load_lds(
        (const __attribute__((address_space(1))) void*)g_src,
        (__attribute__((address_space(3))) void*)lds_dst,
        16, 0, 0);
}

// ---------------- concat + cast: x_bf16[4096][416] (cols 410..415 = 0) ----------------
__global__ void concat_cast_kernel(const float* __restrict__ sf,
                                   const float* __restrict__ ac,
                                   unsigned short* __restrict__ x) {
    int idx = blockIdx.x * blockDim.x + threadIdx.x;
    if (idx >= Bn * KPAD) return;
    int b = idx / KPAD;
    int k = idx - b * KPAD;
    float v = 0.f;
    if (k < OBS) v = sf[b * OBS + k];
    else if (k < IN) v = ac[b * ACTN + (k - OBS)];
    x[idx] = f2bf(v);
}

// ---------------- weight transpose + cast: W[K][N] f32 -> WT[N][Kpad] bf16 ----------------
__global__ __launch_bounds__(256) void transpose_cast(
    const float* __restrict__ W, unsigned short* __restrict__ WT,
    int K, int N, int Kpad, long long gsW, long long gsO)
{
    int g = blockIdx.z;
    W  += (long long)g * gsW;
    WT += (long long)g * gsO;
    __shared__ float tile[32][33];
    int tx = threadIdx.x & 31, ty = threadIdx.x >> 5;   // 32 x 8
    int k0 = blockIdx.y * 32, n0 = blockIdx.x * 32;
#pragma unroll
    for (int i = 0; i < 4; ++i) {
        int k = k0 + ty + i * 8;
        tile[ty + i * 8][tx] = (k < K) ? W[(long long)k * N + n0 + tx] : 0.f;
    }
    __syncthreads();
#pragma unroll
    for (int i = 0; i < 4; ++i) {
        int n = n0 + ty + i * 8;
        WT[(long long)n * Kpad + k0 + tx] = f2bf(tile[tx][ty + i * 8]);
    }
}

// ---------------- query = tanh(emb[task_id]) ----------------
__global__ void query_kernel(const float* __restrict__ emb,
                             const int* __restrict__ task_id,
                             float* __restrict__ query) {
    int idx = blockIdx.x * blockDim.x + threadIdx.x;
    int b = idx >> 8;
    int d = idx & 255;
    query[idx] = tanhf(emb[task_id[b] * D + d]);
}

// ---------------- bf16 MFMA GEMM: C = act(A[M][K] @ BT[N][K]^T + bias) ----------------
// 128x128 tile, BK=32, 4 waves (2x2 of 64x64), 4x4 16x16x32 fragments.
// A, BT row-major with ld == K (multiple of 32). M,N multiples of 128.
// LDS layout per tile [128 rows][4 slots of 16B], slot_store = chunk ^ ((row>>1)&3).
template <int ACTF, int OUTF>   // ACTF: 1=ReLU; OUTF: 0=f32 out, 1=bf16 out
__global__ __launch_bounds__(256) void gemm_bf16(
    const unsigned short* __restrict__ A, const unsigned short* __restrict__ BT,
    const float* __restrict__ bias, void* __restrict__ Cout,
    int K, int ldc,
    long long gsA, long long gsBT, long long gsBias, long long gsC)
{
    const int g = blockIdx.z;
    A    += (long long)g * gsA;
    BT   += (long long)g * gsBT;
    bias += (long long)g * gsBias;
    float*          Cf = (float*)Cout + (long long)g * gsC;
    unsigned short* Cb = (unsigned short*)Cout + (long long)g * gsC;

    __shared__ alignas(16) char smem[16384];   // A: [0,8K), B: [8K,16K)
    const int t  = threadIdx.x;
    const int w  = t >> 6, l = t & 63;
    const int lr = l & 15, lk = l >> 4;
    const int gm = blockIdx.y * 128, gn = blockIdx.x * 128;
    const int wm = (w >> 1) * 64,   wn = (w & 1) * 64;

    // staging: thread t covers tile row sr (round 0) / sr+64 (round 1), 16B slot t&3
    const int sr  = t >> 2;
    const int sc0 = (t & 3) ^ ((sr >> 1) & 3);    // pre-swizzled source chunk (same for sr+64)

    const unsigned short* ga0 = A  + (long long)(gm + sr) * K + sc0 * 8;
    const unsigned short* ga1 = A  + (long long)(gm + sr + 64) * K + sc0 * 8;
    const unsigned short* gb0 = BT + (long long)(gn + sr) * K + sc0 * 8;
    const unsigned short* gb1 = BT + (long long)(gn + sr + 64) * K + sc0 * 8;
    char* dA0 = smem + w * 1024;
    char* dA1 = smem + 4096  + w * 1024;
    char* dB0 = smem + 8192  + w * 1024;
    char* dB1 = smem + 12288 + w * 1024;

    // fragment read offsets (swizzled); row-invariant swz since mi*16>>1 ≡ 0 mod 4
    const int swz  = (lr >> 1) & 3;
    const int aoff = (wm + lr) * 64 + ((lk ^ swz) * 16);
    const int boff = 8192 + (wn + lr) * 64 + ((lk ^ swz) * 16);

    f32x4 acc[4][4] = {};

    for (int k0 = 0; k0 < K; k0 += 32) {
        gload16(dA0, ga0 + k0);
        gload16(dA1, ga1 + k0);
        gload16(dB0, gb0 + k0);
        gload16(dB1, gb1 + k0);
        __syncthreads();

        bf16x8 af[4], bfr[4];
#pragma unroll
        for (int i = 0; i < 4; ++i) {
            af[i]  = *(const bf16x8*)(smem + aoff + i * 1024);
            bfr[i] = *(const bf16x8*)(smem + boff + i * 1024);
        }
#pragma unroll
        for (int mi = 0; mi < 4; ++mi)
#pragma unroll
            for (int ni = 0; ni < 4; ++ni)
                acc[mi][ni] = __builtin_amdgcn_mfma_f32_16x16x32_bf16(
                    af[mi], bfr[ni], acc[mi][ni], 0, 0, 0);
        __syncthreads();
    }

    // epilogue: D col = lane&15, row = 4*(lane>>4)+r
    const int orow0 = gm + wm + lk * 4;
    const int ocol0 = gn + wn + lr;
    float bv[4];
#pragma unroll
    for (int ni = 0; ni < 4; ++ni) bv[ni] = bias[ocol0 - gm + ni * 16 + gn - gn + (wn + lr + ni * 16) - (wn + lr + ni * 16)] , bv[ni] = bias[gn + wn + lr + ni * 16 - gn + gn - gn + 0 + 0] , bv[ni] = bias[gn + wn + lr + ni * 16];
#pragma unroll
    for (int mi = 0; mi < 4; ++mi) {
#pragma unroll
        for (int ni = 0; ni < 4; ++ni) {
#pragma unroll
            for (int r = 0; r < 4; ++r) {
                float v = acc[mi][ni][r] + bv[ni];
                if (ACTF == 1) v = fmaxf(v, 0.f);
                long long off = (long long)(orow0 + mi * 16 + r) * ldc + ocol0 + ni * 16;
                if (OUTF == 0) Cf[off] = v;
                else           Cb[off] = f2bf(v);
            }
        }
    }
}

// ---------------- attention (keys/vals bf16): softmax + weighted sum + loss partials ----------------
__global__ __launch_bounds__(256) void attn_kernel(
    const float* __restrict__ query, const unsigned short* __restrict__ keys,
    const unsigned short* __restrict__ vals, unsigned short* __restrict__ tower_in,
    float* __restrict__ loss_partial)
{
    int wv   = threadIdx.x >> 6;
    int lane = threadIdx.x & 63;
    int b    = blockIdx.x * 4 + wv;
    int d0   = lane * 4;

    const float4 q4 = *(const float4*)&query[(long long)b * D + d0];

    float s[E];
#pragma unroll
    for (int e = 0; e < E; ++e) {
        uint2 kk = *(const uint2*)&keys[((long long)e * Bn + b) * D + d0];
        float k0 = __uint_as_float(kk.x << 16);
        float k1 = __uint_as_float(kk.x & 0xffff0000u);
        float k2 = __uint_as_float(kk.y << 16);
        float k3 = __uint_as_float(kk.y & 0xffff0000u);
        float p = q4.x * k0 + q4.y * k1 + q4.z * k2 + q4.w * k3;
#pragma unroll
        for (int off = 32; off > 0; off >>= 1) p += __shfl_xor(p, off, 64);
        s[e] = p;
    }

    float m = s[0];
#pragma unroll
    for (int e = 1; e < E; ++e) m = fmaxf(m, s[e]);
    float wgt[E];
    float sum = 0.f;
#pragma unroll
    for (int e = 0; e < E; ++e) { wgt[e] = expf(s[e] - m); sum += wgt[e]; }
    float inv = 1.f / sum;

    float4 acc = make_float4(0.f, 0.f, 0.f, 0.f);
    float lb = 0.f;
#pragma unroll
    for (int e = 0; e < E; ++e) {
        float we = wgt[e] * inv;
        uint2 vv = *(const uint2*)&vals[((long long)e * Bn + b) * D + d0];
        acc.x += we * __uint_as_float(vv.x << 16);
        acc.y += we * __uint_as_float(vv.x & 0xffff0000u);
        acc.z += we * __uint_as_float(vv.y << 16);
        acc.w += we * __uint_as_float(vv.y & 0xffff0000u);
        lb += fminf(fmaxf(logf(we + 1e-10f), -6.f), 0.f);
    }
    ushort4 o;
    o.x = f2bf(acc.x); o.y = f2bf(acc.y); o.z = f2bf(acc.z); o.w = f2bf(acc.w);
    *(ushort4*)&tower_in[(long long)b * D + d0] = o;

    __shared__ float sm[4];
    if (lane == 0) sm[wv] = lb;
    __syncthreads();
    if (threadIdx.x == 0)
        loss_partial[blockIdx.x] = sm[0] + sm[1] + sm[2] + sm[3];
}

// ---------------- q = t2 @ tW3 + tb3 ----------------
__global__ __launch_bounds__(256) void qdot_kernel(
    const float* __restrict__ t2, const float* __restrict__ tW3,
    const float* __restrict__ tb3, float* __restrict__ out)
{
    int wv   = threadIdx.x >> 6;
    int lane = threadIdx.x & 63;
    int b    = blockIdx.x * 4 + wv;
    int d0   = lane * 4;
    float4 h4 = *(const float4*)&t2[(long long)b * D + d0];
    float4 w4 = *(const float4*)&tW3[d0];
    float p = h4.x * w4.x + h4.y * w4.y + h4.z * w4.z + h4.w * w4.w;
#pragma unroll
    for (int off = 32; off > 0; off >>= 1) p += __shfl_xor(p, off, 64);
    if (lane == 0) out[b] = p + tb3[0];
}

// ---------------- final loss reduce ----------------
__global__ __launch_bounds__(256) void loss_reduce(const float* __restrict__ partial,
                                                   float* __restrict__ out) {
    float s = 0.f;
    for (int i = threadIdx.x; i < Bn / 4; i += 256) s += partial[i];
#pragma unroll
    for (int off = 32; off > 0; off >>= 1) s += __shfl_xor(s, off, 64);
    __shared__ float sm[4];
    if ((threadIdx.x & 63) == 0) sm[threadIdx.x >> 6] = s;
    __syncthreads();
    if (threadIdx.x == 0) out[0] = (-0.3f / Bn) * (sm[0] + sm[1] + sm[2] + sm[3]);
}

extern "C" void kernel_launch(void* const* d_in, const int* in_sizes, int n_in,
                              void* d_out, int out_size, void* d_ws, size_t ws_size,
                              hipStream_t stream) {
    const float* state_feat = (const float*)d_in[0];
    const float* act        = (const float*)d_in[1];
    const int*   task_id    = (const int*)d_in[2];
    const float* rep_W1 = (const float*)d_in[3];
    const float* rep_b1 = (const float*)d_in[4];
    const float* rep_W2 = (const float*)d_in[5];
    const float* rep_b2 = (const float*)d_in[6];
    const float* emb    = (const float*)d_in[7];
    const float* kW1 = (const float*)d_in[8];
    const float* kb1 = (const float*)d_in[9];
    const float* kW2 = (const float*)d_in[10];
    const float* kb2 = (const float*)d_in[11];
    const float* vW1 = (const float*)d_in[12];
    const float* vb1 = (const float*)d_in[13];
    const float* vW2 = (const float*)d_in[14];
    const float* vb2 = (const float*)d_in[15];
    const float* tW1 = (const float*)d_in[16];
    const float* tb1 = (const float*)d_in[17];
    const float* tW2 = (const float*)d_in[18];
    const float* tb2 = (const float*)d_in[19];
    const float* tW3 = (const float*)d_in[20];
    const float* tb3 = (const float*)d_in[21];
    float* out = (float*)d_out;

    // ---- workspace layout (bytes, 256-aligned chunks) ----
    char* p = (char*)d_ws;
    auto alloc = [&](size_t bytes) {
        char* r = p;
        p += (bytes + 255) & ~(size_t)255;
        return r;
    };
    unsigned short* x       = (unsigned short*)alloc((size_t)Bn * KPAD * 2);
    unsigned short* repW1T  = (unsigned short*)alloc((size_t)H1 * KPAD * 2);
    unsigned short* repW2T  = (unsigned short*)alloc((size_t)H1 * H1 * 2);
    unsigned short* kW1T    = (unsigned short*)alloc((size_t)E * H2 * H1 * 2);
    unsigned short* kW2T    = (unsigned short*)alloc((size_t)E * D * H2 * 2);
    unsigned short* vW1T    = (unsigned short*)alloc((size_t)E * H2 * H1 * 2);
    unsigned short* vW2T    = (unsigned short*)alloc((size_t)E * D * H2 * 2);
    unsigned short* tW1T    = (unsigned short*)alloc((size_t)D * D * 2);
    unsigned short* tW2T    = (unsigned short*)alloc((size_t)D * D * 2);
    char*           h1zone  = alloc((size_t)Bn * H1 * 2);          // h1, later tower bufs
    unsigned short* rep     = (unsigned short*)alloc((size_t)Bn * H1 * 2);
    unsigned short* hk      = (unsigned short*)alloc((size_t)E * Bn * H2 * 2);
    unsigned short* keys    = (unsigned short*)alloc((size_t)E * Bn * D * 2);
    unsigned short* vals    = (unsigned short*)alloc((size_t)E * Bn * D * 2);
    float*          query   = (float*)alloc((size_t)Bn * D * 4);
    float*          lossp   = (float*)alloc((size_t)(Bn / 4) * 4);

    unsigned short* h1       = (unsigned short*)h1zone;            // [4096][1024] bf16
    unsigned short* tower_in = (unsigned short*)h1zone;            // [4096][256] bf16 (h1 dead)
    unsigned short* t1       = (unsigned short*)(h1zone + (size_t)Bn * D * 2);
    float*          t2       = (float*)(h1zone + (size_t)2 * Bn * D * 2);

    // ---- 1. weight transpose-casts ----
    transpose_cast<<<dim3(H1 / 32, KPAD / 32, 1), 256, 0, stream>>>(rep_W1, repW1T, IN, H1, KPAD, 0, 0);
    transpose_cast<<<dim3(H1 / 32, H1 / 32, 1), 256, 0, stream>>>(rep_W2, repW2T, H1, H1, H1, 0, 0);
    transpose_cast<<<dim3(H2 / 32, H1 / 32, E), 256, 0, stream>>>(kW1, kW1T, H1, H2, H1,
        (long long)H1 * H2, (long long)H2 * H1);
    transpose_cast<<<dim3(D / 32, H2 / 32, E), 256, 0, stream>>>(kW2, kW2T, H2, D, H2,
        (long long)H2 * D, (long long)D * H2);
    transpose_cast<<<dim3(H2 / 32, H1 / 32, E), 256, 0, stream>>>(vW1, vW1T, H1, H2, H1,
        (long long)H1 * H2, (long long)H2 * H1);
    transpose_cast<<<dim3(D / 32, H2 / 32, E), 256, 0, stream>>>(vW2, vW2T, H2, D, H2,
        (long long)H2 * D, (long long)D * H2);
    transpose_cast<<<dim3(D / 32, D / 32, 1), 256, 0, stream>>>(tW1, tW1T, D, D, D, 0, 0);
    transpose_cast<<<dim3(D / 32, D / 32, 1), 256, 0, stream>>>(tW2, tW2T, D, D, D, 0, 0);

    // ---- 2. concat + cast ----
    concat_cast_kernel<<<(Bn * KPAD + 255) / 256, 256, 0, stream>>>(state_feat, act, x);
    // ---- 3. query ----
    query_kernel<<<(Bn * D) / 256, 256, 0, stream>>>(emb, task_id, query);

    // ---- 4. h1 = ReLU(x @ rep_W1 + b1) ----
    gemm_bf16<1, 1><<<dim3(H1 / 128, Bn / 128, 1), 256, 0, stream>>>(
        x, repW1T, rep_b1, h1, KPAD, H1, 0, 0, 0, 0);
    // ---- 5. rep = h1 @ rep_W2 + b2 ----
    gemm_bf16<0, 1><<<dim3(H1 / 128, Bn / 128, 1), 256, 0, stream>>>(
        h1, repW2T, rep_b2, rep, H1, H1, 0, 0, 0, 0);

    // ---- 6. expert K path ----
    gemm_bf16<1, 1><<<dim3(H2 / 128, Bn / 128, E), 256, 0, stream>>>(
        rep, kW1T, kb1, hk, H1, H2, 0, (long long)H2 * H1, H2, (long long)Bn * H2);
    gemm_bf16<0, 1><<<dim3(D / 128, Bn / 128, E), 256, 0, stream>>>(
        hk, kW2T, kb2, keys, H2, D, (long long)Bn * H2, (long long)D * H2, D, (long long)Bn * D);
    // ---- 7. expert V path (reuse hk buffer) ----
    gemm_bf16<1, 1><<<dim3(H2 / 128, Bn / 128, E), 256, 0, stream>>>(
        rep, vW1T, vb1, hk, H1, H2, 0, (long long)H2 * H1, H2, (long long)Bn * H2);
    gemm_bf16<0, 1><<<dim3(D / 128, Bn / 128, E), 256, 0, stream>>>(
        hk, vW2T, vb2, vals, H2, D, (long long)Bn * H2, (long long)D * H2, D, (long long)Bn * D);

    // ---- 8. attention ----
    attn_kernel<<<Bn / 4, 256, 0, stream>>>(query, keys, vals, tower_in, lossp);

    // ---- 9. tower ----
    gemm_bf16<1, 1><<<dim3(D / 128, Bn / 128, 1), 256, 0, stream>>>(
        tower_in, tW1T, tb1, t1, D, D, 0, 0, 0, 0);
    gemm_bf16<1, 0><<<dim3(D / 128, Bn / 128, 1), 256, 0, stream>>>(
        t1, tW2T, tb2, t2, D, D, 0, 0, 0, 0);

    // ---- 10. q + loss ----
    qdot_kernel<<<Bn / 4, 256, 0, stream>>>(t2, tW3, tb3, out);
    loss_reduce<<<1, 256, 0, stream>>>(lossp, out + Bn);
}

// Round 3
// 200.329 us; speedup vs baseline: 9.5412x; 1.3005x over previous
//
#include <hip/hip_runtime.h>

constexpr int Bn   = 4096;
constexpr int OBS  = 390;
constexpr int ACTN = 20;
constexpr int IN   = 410;   // OBS + ACTN
constexpr int KPAD = 416;   // IN padded to multiple of 32
constexpr int E    = 8;
constexpr int H1   = 1024;
constexpr int H2   = 512;
constexpr int D    = 256;

typedef __bf16 bf16x8 __attribute__((ext_vector_type(8)));
typedef float  f32x4  __attribute__((ext_vector_type(4)));

__device__ __forceinline__ unsigned short f2bf(float f) {
    unsigned int u = __float_as_uint(f);
    unsigned int r = u + 0x7fffu + ((u >> 16) & 1u);   // RNE
    return (unsigned short)(r >> 16);
}
__device__ __forceinline__ void gload16(void* lds_dst, const void* g_src) {
    __builtin_amdgcn_global_load_lds(
        (const __attribute__((address_space(1))) void*)g_src,
        (__attribute__((address_space(3))) void*)lds_dst,
        16, 0, 0);
}

// ---------------- prep: concat+cast x, query = tanh(emb[task_id]) ----------------
__global__ void prep_kernel(const float* __restrict__ sf, const float* __restrict__ ac,
                            unsigned short* __restrict__ x,
                            const float* __restrict__ emb, const int* __restrict__ task_id,
                            float* __restrict__ query) {
    int idx = blockIdx.x * blockDim.x + threadIdx.x;
    if (idx < Bn * KPAD) {
        int b = idx / KPAD;
        int k = idx - b * KPAD;
        float v = 0.f;
        if (k < OBS) v = sf[b * OBS + k];
        else if (k < IN) v = ac[b * ACTN + (k - OBS)];
        x[idx] = f2bf(v);
    } else {
        int j = idx - Bn * KPAD;           // < Bn*D by grid construction
        int b = j >> 8;
        int d = j & 255;
        query[j] = tanhf(emb[task_id[b] * D + d]);
    }
}

// ---------------- mega transpose+cast: W[K][N] f32 -> WT[N][Kpad] bf16, 8 descs ----------------
struct TDesc {
    const float* W;
    unsigned short* WT;
    int K, N, Kpad;
    long long gsW, gsO;
    int tilesX, tilesY, perG;   // perG = tilesX*tilesY
    int start;
};
struct TDescArr { TDesc d[8]; };

__global__ __launch_bounds__(256) void mega_transpose(TDescArr da) {
    int bid = blockIdx.x;
    int i = 0;
#pragma unroll
    for (int j = 1; j < 8; ++j) if (bid >= da.d[j].start) i = j;
    TDesc dd = da.d[i];
    int local = bid - dd.start;
    int g   = local / dd.perG;
    int rem = local - g * dd.perG;
    int tyt = rem / dd.tilesX;
    int txt = rem - tyt * dd.tilesX;
    const float* W = dd.W + (long long)g * dd.gsW;
    unsigned short* WT = dd.WT + (long long)g * dd.gsO;

    __shared__ float tile[32][33];
    int tx = threadIdx.x & 31, ty = threadIdx.x >> 5;
    int k0 = tyt * 32, n0 = txt * 32;
#pragma unroll
    for (int r = 0; r < 4; ++r) {
        int k = k0 + ty + r * 8;
        tile[ty + r * 8][tx] = (k < dd.K) ? W[(long long)k * dd.N + n0 + tx] : 0.f;
    }
    __syncthreads();
#pragma unroll
    for (int r = 0; r < 4; ++r) {
        int n = n0 + ty + r * 8;
        WT[(long long)n * dd.Kpad + k0 + tx] = f2bf(tile[tx][ty + r * 8]);
    }
}

// ---------------- bias concat: [kb1|vb1] -> b1cat[16][H2], [kb2|vb2] -> b2cat[16][D] ----------------
__global__ void bias_concat(const float* __restrict__ kb1, const float* __restrict__ vb1,
                            const float* __restrict__ kb2, const float* __restrict__ vb2,
                            float* __restrict__ b1cat, float* __restrict__ b2cat) {
    int i = blockIdx.x * blockDim.x + threadIdx.x;
    if (i < E * H2)            b1cat[i] = kb1[i];
    else if (i < 2 * E * H2)   b1cat[i] = vb1[i - E * H2];
    else {
        int j = i - 2 * E * H2;
        if (j < E * D)         b2cat[j] = kb2[j];
        else                   b2cat[j] = vb2[j - E * D];
    }
}

// ---------------- bf16 MFMA GEMM: C = act(A[M][K] @ BT[N][K]^T + bias) ----------------
// 128x128 tile, 4 waves (2x2 of 64x64), 4x4 16x16x32 fragments, BK in {32,64}.
// LDS [128 rows][CH chunks of 16B], stored chunk c holds global chunk c ^ swz(row).
template <int ACTF, int OUTF, int BK>   // ACTF: 1=ReLU; OUTF: 0=f32 out, 1=bf16 out
__global__ __launch_bounds__(256) void gemm_bf16(
    const unsigned short* __restrict__ A, const unsigned short* __restrict__ BT,
    const float* __restrict__ bias, void* __restrict__ Cout,
    int K, int ldc,
    long long gsA, long long gsBT, long long gsBias, long long gsC)
{
    constexpr int CH   = BK / 8;        // 16B chunks per row: 4 or 8
    constexpr int RPR  = 256 / CH;      // rows per staging round: 64 or 32
    constexpr int RNDS = 128 / RPR;     // staging rounds per tile: 2 or 4
    constexpr int TB   = 128 * BK * 2;  // tile bytes: 8K or 16K
    constexpr int RS   = CH * 16;       // LDS row stride bytes: 64 or 128

    const int g = blockIdx.z;
    A    += (long long)g * gsA;
    BT   += (long long)g * gsBT;
    bias += (long long)g * gsBias;
    float*          Cf = (float*)Cout + (long long)g * gsC;
    unsigned short* Cb = (unsigned short*)Cout + (long long)g * gsC;

    __shared__ alignas(16) char smem[2 * TB];
    const int t  = threadIdx.x;
    const int w  = t >> 6, l = t & 63;
    const int lr = l & 15, lk = l >> 4;
    const int gm = blockIdx.y * 128, gn = blockIdx.x * 128;
    const int wm = (w >> 1) * 64,   wn = (w & 1) * 64;

    // staging: thread t covers row srow (+ j*RPR per round), source chunk pre-swizzled
    const int srow = t / CH;
    const int swzS = (CH == 8) ? (srow & 7) : ((srow >> 1) & 3);
    const int sc   = (t % CH) ^ swzS;
    const unsigned short* gA = A  + (long long)(gm + srow) * K + sc * 8;
    const unsigned short* gB = BT + (long long)(gn + srow) * K + sc * 8;

    // fragment read offsets (swz depends only on lr)
    const int swzL = (CH == 8) ? (lr & 7) : ((lr >> 1) & 3);
    const int aoff = (wm + lr) * RS + ((lk ^ swzL) * 16);
    const int boff = TB + (wn + lr) * RS + ((lk ^ swzL) * 16);

    f32x4 acc[4][4] = {};

    for (int k0 = 0; k0 < K; k0 += BK) {
#pragma unroll
        for (int j = 0; j < RNDS; ++j) {
            gload16(smem + j * 4096 + w * 1024,      gA + k0 + (long long)j * RPR * K);
            gload16(smem + TB + j * 4096 + w * 1024, gB + k0 + (long long)j * RPR * K);
        }
        __syncthreads();

        bf16x8 af[4], bfr[4];
#pragma unroll
        for (int i = 0; i < 4; ++i) {
            af[i]  = *(const bf16x8*)(smem + aoff + i * 16 * RS);
            bfr[i] = *(const bf16x8*)(smem + boff + i * 16 * RS);
        }
#pragma unroll
        for (int mi = 0; mi < 4; ++mi)
#pragma unroll
            for (int ni = 0; ni < 4; ++ni)
                acc[mi][ni] = __builtin_amdgcn_mfma_f32_16x16x32_bf16(
                    af[mi], bfr[ni], acc[mi][ni], 0, 0, 0);

        if constexpr (BK == 64) {
            // second 32-K half: chunk index += 4  <=>  byte offset ^ 64
#pragma unroll
            for (int i = 0; i < 4; ++i) {
                af[i]  = *(const bf16x8*)(smem + (aoff ^ 64) + i * 16 * RS);
                bfr[i] = *(const bf16x8*)(smem + (boff ^ 64) + i * 16 * RS);
            }
#pragma unroll
            for (int mi = 0; mi < 4; ++mi)
#pragma unroll
                for (int ni = 0; ni < 4; ++ni)
                    acc[mi][ni] = __builtin_amdgcn_mfma_f32_16x16x32_bf16(
                        af[mi], bfr[ni], acc[mi][ni], 0, 0, 0);
        }
        __syncthreads();
    }

    // epilogue: D col = lane&15, row = 4*(lane>>4)+r
    const int orow0 = gm + wm + lk * 4;
    const int ocol0 = gn + wn + lr;
    float bv[4];
#pragma unroll
    for (int ni = 0; ni < 4; ++ni) bv[ni] = bias[gn + wn + lr + ni * 16];
#pragma unroll
    for (int mi = 0; mi < 4; ++mi)
#pragma unroll
        for (int ni = 0; ni < 4; ++ni)
#pragma unroll
            for (int r = 0; r < 4; ++r) {
                float v = acc[mi][ni][r] + bv[ni];
                if (ACTF == 1) v = fmaxf(v, 0.f);
                long long off = (long long)(orow0 + mi * 16 + r) * ldc + ocol0 + ni * 16;
                if (OUTF == 0) Cf[off] = v;
                else           Cb[off] = f2bf(v);
            }
}

// ---------------- attention (keys/vals bf16 slabs of kv): softmax + weighted sum + loss ----------------
__global__ __launch_bounds__(256) void attn_kernel(
    const float* __restrict__ query, const unsigned short* __restrict__ keys,
    const unsigned short* __restrict__ vals, unsigned short* __restrict__ tower_in,
    float* __restrict__ loss_partial)
{
    int wv   = threadIdx.x >> 6;
    int lane = threadIdx.x & 63;
    int b    = blockIdx.x * 4 + wv;
    int d0   = lane * 4;

    const float4 q4 = *(const float4*)&query[(long long)b * D + d0];

    float s[E];
#pragma unroll
    for (int e = 0; e < E; ++e) {
        uint2 kk = *(const uint2*)&keys[((long long)e * Bn + b) * D + d0];
        float k0 = __uint_as_float(kk.x << 16);
        float k1 = __uint_as_float(kk.x & 0xffff0000u);
        float k2 = __uint_as_float(kk.y << 16);
        float k3 = __uint_as_float(kk.y & 0xffff0000u);
        float p = q4.x * k0 + q4.y * k1 + q4.z * k2 + q4.w * k3;
#pragma unroll
        for (int off = 32; off > 0; off >>= 1) p += __shfl_xor(p, off, 64);
        s[e] = p;
    }

    float m = s[0];
#pragma unroll
    for (int e = 1; e < E; ++e) m = fmaxf(m, s[e]);
    float wgt[E];
    float sum = 0.f;
#pragma unroll
    for (int e = 0; e < E; ++e) { wgt[e] = expf(s[e] - m); sum += wgt[e]; }
    float inv = 1.f / sum;

    float4 acc = make_float4(0.f, 0.f, 0.f, 0.f);
    float lb = 0.f;
#pragma unroll
    for (int e = 0; e < E; ++e) {
        float we = wgt[e] * inv;
        uint2 vv = *(const uint2*)&vals[((long long)e * Bn + b) * D + d0];
        acc.x += we * __uint_as_float(vv.x << 16);
        acc.y += we * __uint_as_float(vv.x & 0xffff0000u);
        acc.z += we * __uint_as_float(vv.y << 16);
        acc.w += we * __uint_as_float(vv.y & 0xffff0000u);
        lb += fminf(fmaxf(logf(we + 1e-10f), -6.f), 0.f);
    }
    ushort4 o;
    o.x = f2bf(acc.x); o.y = f2bf(acc.y); o.z = f2bf(acc.z); o.w = f2bf(acc.w);
    *(ushort4*)&tower_in[(long long)b * D + d0] = o;

    __shared__ float sm[4];
    if (lane == 0) sm[wv] = lb;
    __syncthreads();
    if (threadIdx.x == 0)
        loss_partial[blockIdx.x] = sm[0] + sm[1] + sm[2] + sm[3];
}

// ---------------- q = t2 @ tW3 + tb3 ; block 1024 does loss reduce ----------------
__global__ __launch_bounds__(256) void qdot_loss_kernel(
    const float* __restrict__ t2, const float* __restrict__ tW3,
    const float* __restrict__ tb3, float* __restrict__ out,
    const float* __restrict__ lossp)
{
    if (blockIdx.x == Bn / 4) {
        float s = 0.f;
        for (int i = threadIdx.x; i < Bn / 4; i += 256) s += lossp[i];
#pragma unroll
        for (int off = 32; off > 0; off >>= 1) s += __shfl_xor(s, off, 64);
        __shared__ float sm[4];
        if ((threadIdx.x & 63) == 0) sm[threadIdx.x >> 6] = s;
        __syncthreads();
        if (threadIdx.x == 0) out[Bn] = (-0.3f / Bn) * (sm[0] + sm[1] + sm[2] + sm[3]);
        return;
    }
    int wv   = threadIdx.x >> 6;
    int lane = threadIdx.x & 63;
    int b    = blockIdx.x * 4 + wv;
    int d0   = lane * 4;
    float4 h4 = *(const float4*)&t2[(long long)b * D + d0];
    float4 w4 = *(const float4*)&tW3[d0];
    float p = h4.x * w4.x + h4.y * w4.y + h4.z * w4.z + h4.w * w4.w;
#pragma unroll
    for (int off = 32; off > 0; off >>= 1) p += __shfl_xor(p, off, 64);
    if (lane == 0) out[b] = p + tb3[0];
}

extern "C" void kernel_launch(void* const* d_in, const int* in_sizes, int n_in,
                              void* d_out, int out_size, void* d_ws, size_t ws_size,
                              hipStream_t stream) {
    const float* state_feat = (const float*)d_in[0];
    const float* act        = (const float*)d_in[1];
    const int*   task_id    = (const int*)d_in[2];
    const float* rep_W1 = (const float*)d_in[3];
    const float* rep_b1 = (const float*)d_in[4];
    const float* rep_W2 = (const float*)d_in[5];
    const float* rep_b2 = (const float*)d_in[6];
    const float* emb    = (const float*)d_in[7];
    const float* kW1 = (const float*)d_in[8];
    const float* kb1 = (const float*)d_in[9];
    const float* kW2 = (const float*)d_in[10];
    const float* kb2 = (const float*)d_in[11];
    const float* vW1 = (const float*)d_in[12];
    const float* vb1 = (const float*)d_in[13];
    const float* vW2 = (const float*)d_in[14];
    const float* vb2 = (const float*)d_in[15];
    const float* tW1 = (const float*)d_in[16];
    const float* tb1 = (const float*)d_in[17];
    const float* tW2 = (const float*)d_in[18];
    const float* tb2 = (const float*)d_in[19];
    const float* tW3 = (const float*)d_in[20];
    const float* tb3 = (const float*)d_in[21];
    float* out = (float*)d_out;

    // ---- workspace ----
    char* p = (char*)d_ws;
    auto alloc = [&](size_t bytes) {
        char* r = p;
        p += (bytes + 255) & ~(size_t)255;
        return r;
    };
    // fused path needs ~143 MB; serial path reuses hkv K-slab region (~111 MB)
    bool fused = ws_size >= (size_t)150 * 1024 * 1024;

    unsigned short* x      = (unsigned short*)alloc((size_t)Bn * KPAD * 2);
    unsigned short* repW1T = (unsigned short*)alloc((size_t)H1 * KPAD * 2);
    unsigned short* repW2T = (unsigned short*)alloc((size_t)H1 * H1 * 2);
    unsigned short* w1T    = (unsigned short*)alloc((size_t)2 * E * H2 * H1 * 2);
    unsigned short* w2T    = (unsigned short*)alloc((size_t)2 * E * D * H2 * 2);
    unsigned short* tW1T   = (unsigned short*)alloc((size_t)D * D * 2);
    unsigned short* tW2T   = (unsigned short*)alloc((size_t)D * D * 2);
    float*          b1cat  = (float*)alloc((size_t)2 * E * H2 * 4);
    float*          b2cat  = (float*)alloc((size_t)2 * E * D * 4);
    char*           h1zone = alloc((size_t)Bn * H1 * 2);
    unsigned short* rep    = (unsigned short*)alloc((size_t)Bn * H1 * 2);
    unsigned short* hkv    = (unsigned short*)alloc((size_t)(fused ? 2 * E : E) * Bn * H2 * 2);
    unsigned short* kv     = (unsigned short*)alloc((size_t)2 * E * Bn * D * 2);
    float*          query  = (float*)alloc((size_t)Bn * D * 4);
    float*          lossp  = (float*)alloc((size_t)(Bn / 4) * 4);

    unsigned short* h1       = (unsigned short*)h1zone;
    unsigned short* tower_in = (unsigned short*)h1zone;
    unsigned short* t1       = (unsigned short*)(h1zone + (size_t)Bn * D * 2);
    float*          t2       = (float*)(h1zone + (size_t)2 * Bn * D * 2);

    // ---- 1. mega transpose-cast (1 launch) ----
    TDescArr da;
    int startAcc = 0;
    auto setd = [&](int i, const float* W, unsigned short* WT, int K, int N, int Kpad,
                    long long gsW, long long gsO, int groups) {
        TDesc& dd = da.d[i];
        dd.W = W; dd.WT = WT; dd.K = K; dd.N = N; dd.Kpad = Kpad;
        dd.gsW = gsW; dd.gsO = gsO;
        dd.tilesX = N / 32; dd.tilesY = Kpad / 32;
        dd.perG = dd.tilesX * dd.tilesY;
        dd.start = startAcc;
        startAcc += dd.perG * groups;
    };
    setd(0, rep_W1, repW1T, IN, H1, KPAD, 0, 0, 1);
    setd(1, rep_W2, repW2T, H1, H1, H1, 0, 0, 1);
    setd(2, kW1, w1T,                               H1, H2, H1, (long long)H1 * H2, (long long)H2 * H1, E);
    setd(3, vW1, w1T + (size_t)E * H2 * H1,         H1, H2, H1, (long long)H1 * H2, (long long)H2 * H1, E);
    setd(4, kW2, w2T,                               H2, D, H2, (long long)H2 * D, (long long)D * H2, E);
    setd(5, vW2, w2T + (size_t)E * D * H2,          H2, D, H2, (long long)H2 * D, (long long)D * H2, E);
    setd(6, tW1, tW1T, D, D, D, 0, 0, 1);
    setd(7, tW2, tW2T, D, D, D, 0, 0, 1);
    mega_transpose<<<startAcc, 256, 0, stream>>>(da);

    // ---- 2. bias concat + prep (2 launches) ----
    bias_concat<<<(2 * E * H2 + 2 * E * D) / 256, 256, 0, stream>>>(
        kb1, vb1, kb2, vb2, b1cat, b2cat);
    prep_kernel<<<(Bn * KPAD + Bn * D) / 256, 256, 0, stream>>>(
        state_feat, act, x, emb, task_id, query);

    // ---- 3. rep MLP ----
    gemm_bf16<1, 1, 32><<<dim3(H1 / 128, Bn / 128, 1), 256, 0, stream>>>(
        x, repW1T, rep_b1, h1, KPAD, H1, 0, 0, 0, 0);
    gemm_bf16<0, 1, 64><<<dim3(H1 / 128, Bn / 128, 1), 256, 0, stream>>>(
        h1, repW2T, rep_b2, rep, H1, H1, 0, 0, 0, 0);

    // ---- 4. expert K/V MLPs ----
    if (fused) {
        gemm_bf16<1, 1, 64><<<dim3(H2 / 128, Bn / 128, 2 * E), 256, 0, stream>>>(
            rep, w1T, b1cat, hkv, H1, H2,
            0, (long long)H2 * H1, H2, (long long)Bn * H2);
        gemm_bf16<0, 1, 64><<<dim3(D / 128, Bn / 128, 2 * E), 256, 0, stream>>>(
            hkv, w2T, b2cat, kv, H2, D,
            (long long)Bn * H2, (long long)D * H2, D, (long long)Bn * D);
    } else {
        for (int half = 0; half < 2; ++half) {
            gemm_bf16<1, 1, 64><<<dim3(H2 / 128, Bn / 128, E), 256, 0, stream>>>(
                rep, w1T + (size_t)half * E * H2 * H1, b1cat + half * E * H2, hkv, H1, H2,
                0, (long long)H2 * H1, H2, (long long)Bn * H2);
            gemm_bf16<0, 1, 64><<<dim3(D / 128, Bn / 128, E), 256, 0, stream>>>(
                hkv, w2T + (size_t)half * E * D * H2, b2cat + half * E * D,
                kv + (size_t)half * E * Bn * D, H2, D,
                (long long)Bn * H2, (long long)D * H2, D, (long long)Bn * D);
        }
    }

    // ---- 5. attention ----
    attn_kernel<<<Bn / 4, 256, 0, stream>>>(
        query, kv, kv + (size_t)E * Bn * D, tower_in, lossp);

    // ---- 6. tower ----
    gemm_bf16<1, 1, 64><<<dim3(D / 128, Bn / 128, 1), 256, 0, stream>>>(
        tower_in, tW1T, tb1, t1, D, D, 0, 0, 0, 0);
    gemm_bf16<1, 0, 64><<<dim3(D / 128, Bn / 128, 1), 256, 0, stream>>>(
        t1, tW2T, tb2, t2, D, D, 0, 0, 0, 0);

    // ---- 7. q + loss (1 launch) ----
    qdot_loss_kernel<<<Bn / 4 + 1, 256, 0, stream>>>(t2, tW3, tb3, out, lossp);
}

// Round 4
// 174.303 us; speedup vs baseline: 10.9659x; 1.1493x over previous
//
#include <hip/hip_runtime.h>

constexpr int Bn   = 4096;
constexpr int OBS  = 390;
constexpr int ACTN = 20;
constexpr int IN   = 410;   // OBS + ACTN
constexpr int KPAD = 416;   // IN padded to multiple of 32
constexpr int E    = 8;
constexpr int H1   = 1024;
constexpr int H2   = 512;
constexpr int D    = 256;

typedef __bf16 bf16x8 __attribute__((ext_vector_type(8)));
typedef float  f32x4  __attribute__((ext_vector_type(4)));

__device__ __forceinline__ unsigned short f2bf(float f) {
    unsigned int u = __float_as_uint(f);
    unsigned int r = u + 0x7fffu + ((u >> 16) & 1u);   // RNE
    return (unsigned short)(r >> 16);
}
__device__ __forceinline__ void gload16(void* lds_dst, const void* g_src) {
    __builtin_amdgcn_global_load_lds(
        (const __attribute__((address_space(1))) void*)g_src,
        (__attribute__((address_space(3))) void*)lds_dst,
        16, 0, 0);
}

// ---------------- prep: concat+cast x, query = tanh(emb[task_id]) ----------------
__global__ void prep_kernel(const float* __restrict__ sf, const float* __restrict__ ac,
                            unsigned short* __restrict__ x,
                            const float* __restrict__ emb, const int* __restrict__ task_id,
                            float* __restrict__ query) {
    int idx = blockIdx.x * blockDim.x + threadIdx.x;
    if (idx < Bn * KPAD) {
        int b = idx / KPAD;
        int k = idx - b * KPAD;
        float v = 0.f;
        if (k < OBS) v = sf[b * OBS + k];
        else if (k < IN) v = ac[b * ACTN + (k - OBS)];
        x[idx] = f2bf(v);
    } else {
        int j = idx - Bn * KPAD;           // < Bn*D by grid construction
        int b = j >> 8;
        int d = j & 255;
        query[j] = tanhf(emb[task_id[b] * D + d]);
    }
}

// ---------------- mega transpose+cast: W[K][N] f32 -> WT[N][Kpad] bf16, 8 descs ----------------
struct TDesc {
    const float* W;
    unsigned short* WT;
    int K, N, Kpad;
    long long gsW, gsO;
    int tilesX, tilesY, perG;
    int start;
};
struct TDescArr { TDesc d[8]; };

__global__ __launch_bounds__(256) void mega_transpose(TDescArr da) {
    int bid = blockIdx.x;
    int i = 0;
#pragma unroll
    for (int j = 1; j < 8; ++j) if (bid >= da.d[j].start) i = j;
    TDesc dd = da.d[i];
    int local = bid - dd.start;
    int g   = local / dd.perG;
    int rem = local - g * dd.perG;
    int tyt = rem / dd.tilesX;
    int txt = rem - tyt * dd.tilesX;
    const float* W = dd.W + (long long)g * dd.gsW;
    unsigned short* WT = dd.WT + (long long)g * dd.gsO;

    __shared__ float tile[32][33];
    int tx = threadIdx.x & 31, ty = threadIdx.x >> 5;
    int k0 = tyt * 32, n0 = txt * 32;
#pragma unroll
    for (int r = 0; r < 4; ++r) {
        int k = k0 + ty + r * 8;
        tile[ty + r * 8][tx] = (k < dd.K) ? W[(long long)k * dd.N + n0 + tx] : 0.f;
    }
    __syncthreads();
#pragma unroll
    for (int r = 0; r < 4; ++r) {
        int n = n0 + ty + r * 8;
        WT[(long long)n * dd.Kpad + k0 + tx] = f2bf(tile[tx][ty + r * 8]);
    }
}

// ---------------- bias concat ----------------
__global__ void bias_concat(const float* __restrict__ kb1, const float* __restrict__ vb1,
                            const float* __restrict__ kb2, const float* __restrict__ vb2,
                            float* __restrict__ b1cat, float* __restrict__ b2cat) {
    int i = blockIdx.x * blockDim.x + threadIdx.x;
    if (i < E * H2)            b1cat[i] = kb1[i];
    else if (i < 2 * E * H2)   b1cat[i] = vb1[i - E * H2];
    else {
        int j = i - 2 * E * H2;
        if (j < E * D)         b2cat[j] = kb2[j];
        else                   b2cat[j] = vb2[j - E * D];
    }
}

// ---------------- 128x128 bf16 MFMA GEMM (m97 structure), BK in {32,64} ----------------
template <int ACTF, int OUTF, int BK>
__global__ __launch_bounds__(256) void gemm_bf16(
    const unsigned short* __restrict__ A, const unsigned short* __restrict__ BT,
    const float* __restrict__ bias, void* __restrict__ Cout,
    int K, int ldc,
    long long gsA, long long gsBT, long long gsBias, long long gsC)
{
    constexpr int CH   = BK / 8;
    constexpr int RPR  = 256 / CH;
    constexpr int RNDS = 128 / RPR;
    constexpr int TB   = 128 * BK * 2;
    constexpr int RS   = CH * 16;

    const int g = blockIdx.z;
    A    += (long long)g * gsA;
    BT   += (long long)g * gsBT;
    bias += (long long)g * gsBias;
    float*          Cf = (float*)Cout + (long long)g * gsC;
    unsigned short* Cb = (unsigned short*)Cout + (long long)g * gsC;

    __shared__ alignas(16) char smem[2 * TB];
    const int t  = threadIdx.x;
    const int w  = t >> 6, l = t & 63;
    const int lr = l & 15, lk = l >> 4;
    const int gm = blockIdx.y * 128, gn = blockIdx.x * 128;
    const int wm = (w >> 1) * 64,   wn = (w & 1) * 64;

    const int srow = t / CH;
    const int swzS = (CH == 8) ? (srow & 7) : ((srow >> 1) & 3);
    const int sc   = (t % CH) ^ swzS;
    const unsigned short* gA = A  + (long long)(gm + srow) * K + sc * 8;
    const unsigned short* gB = BT + (long long)(gn + srow) * K + sc * 8;

    const int swzL = (CH == 8) ? (lr & 7) : ((lr >> 1) & 3);
    const int aoff = (wm + lr) * RS + ((lk ^ swzL) * 16);
    const int boff = TB + (wn + lr) * RS + ((lk ^ swzL) * 16);

    f32x4 acc[4][4] = {};

    for (int k0 = 0; k0 < K; k0 += BK) {
#pragma unroll
        for (int j = 0; j < RNDS; ++j) {
            gload16(smem + j * 4096 + w * 1024,      gA + k0 + (long long)j * RPR * K);
            gload16(smem + TB + j * 4096 + w * 1024, gB + k0 + (long long)j * RPR * K);
        }
        __syncthreads();

        bf16x8 af[4], bfr[4];
#pragma unroll
        for (int i = 0; i < 4; ++i) {
            af[i]  = *(const bf16x8*)(smem + aoff + i * 16 * RS);
            bfr[i] = *(const bf16x8*)(smem + boff + i * 16 * RS);
        }
#pragma unroll
        for (int mi = 0; mi < 4; ++mi)
#pragma unroll
            for (int ni = 0; ni < 4; ++ni)
                acc[mi][ni] = __builtin_amdgcn_mfma_f32_16x16x32_bf16(
                    af[mi], bfr[ni], acc[mi][ni], 0, 0, 0);

        if constexpr (BK == 64) {
#pragma unroll
            for (int i = 0; i < 4; ++i) {
                af[i]  = *(const bf16x8*)(smem + (aoff ^ 64) + i * 16 * RS);
                bfr[i] = *(const bf16x8*)(smem + (boff ^ 64) + i * 16 * RS);
            }
#pragma unroll
            for (int mi = 0; mi < 4; ++mi)
#pragma unroll
                for (int ni = 0; ni < 4; ++ni)
                    acc[mi][ni] = __builtin_amdgcn_mfma_f32_16x16x32_bf16(
                        af[mi], bfr[ni], acc[mi][ni], 0, 0, 0);
        }
        __syncthreads();
    }

    const int orow0 = gm + wm + lk * 4;
    const int ocol0 = gn + wn + lr;
    float bv[4];
#pragma unroll
    for (int ni = 0; ni < 4; ++ni) bv[ni] = bias[gn + wn + lr + ni * 16];
#pragma unroll
    for (int mi = 0; mi < 4; ++mi)
#pragma unroll
        for (int ni = 0; ni < 4; ++ni)
#pragma unroll
            for (int r = 0; r < 4; ++r) {
                float v = acc[mi][ni][r] + bv[ni];
                if (ACTF == 1) v = fmaxf(v, 0.f);
                long long off = (long long)(orow0 + mi * 16 + r) * ldc + ocol0 + ni * 16;
                if (OUTF == 0) Cf[off] = v;
                else           Cb[off] = f2bf(v);
            }
}

// ---------------- 256x256 8-wave pipelined bf16 GEMM (T3+T4+T5), K%128==0 ----------------
// 2 phases per K-tile(64); counted vmcnt(4) boundary; LDS 128KB double-buffered.
// Buffer c layout: A-unit0 @0, A-unit1 @16K, B-unit0 @32K, B-unit1 @48K; buffer stride 64K.
// Element (row,chunk) of a unit stored at slot row*8 + (chunk ^ (row&7)).
template <int KTOT, int ACTF, int OUTF>
__global__ __launch_bounds__(512, 2) void gemm256(
    const unsigned short* __restrict__ A, const unsigned short* __restrict__ BT,
    const float* __restrict__ bias, void* __restrict__ Cout,
    int ldc, long long gsA, long long gsBT, long long gsBias, long long gsC)
{
    constexpr int NT = KTOT / 64;
    static_assert(NT >= 4 && (NT % 2) == 0, "KTOT must be multiple of 128");

    const int g = blockIdx.z;
    A    += (long long)g * gsA;
    BT   += (long long)g * gsBT;
    bias += (long long)g * gsBias;
    float*          Cf = (float*)Cout + (long long)g * gsC;
    unsigned short* Cb = (unsigned short*)Cout + (long long)g * gsC;

    __shared__ __align__(16) char smem[131072];

    const int tid = threadIdx.x;
    const int l  = tid & 63;
    const int lr = l & 15, lk = l >> 4;
    const int w  = tid >> 6;
    const int wr = w >> 2, wc = w & 3;          // 2 x 4 wave grid; wave tile 128x64
    const int gm = blockIdx.y * 256, gn = blockIdx.x * 256;

    // ---- staging precompute: thread covers slots tid and tid+512 of a 1024-slot unit ----
    const int srow = tid >> 3;                    // 0..63 (j=1 adds 64)
    const int cg   = (tid & 7) ^ (srow & 7);      // pre-swizzled global chunk
    const unsigned short* gA = A  + (long long)(gm + srow) * KTOT + cg * 8;
    const unsigned short* gB = BT + (long long)(gn + srow) * KTOT + cg * 8;
    const int wbase = (tid & ~63) * 16;           // wave-uniform slot base (bytes)

    // ---- ds_read precompute ----
    const int cs0 = ((0 | lk) ^ (lr & 7)) * 16;   // ks=0 chunk byte offset
    const int cs1 = ((4 | lk) ^ (lr & 7)) * 16;   // ks=1
    const int aRow = wr * 16384 + lr * 128;                         // + (mh*64+m*16)*128
    const int bRow = 32768 + (wc >> 1) * 16384 + ((wc & 1) * 64 + lr) * 128;  // + n*16*128

    f32x4 acc[8][4] = {};

    auto stA = [&](int c, int s, int kt) {
        const unsigned short* src = gA + (long long)(s * 128) * KTOT + kt * 64;
        char* d = smem + c * 65536 + s * 16384 + wbase;
        gload16(d,        src);
        gload16(d + 8192, src + (long long)64 * KTOT);
    };
    auto stB = [&](int c, int s, int kt) {
        const unsigned short* src = gB + (long long)(s * 128) * KTOT + kt * 64;
        char* d = smem + c * 65536 + 32768 + s * 16384 + wbase;
        gload16(d,        src);
        gload16(d + 8192, src + (long long)64 * KTOT);
    };

    // ---- prologue: tile0 (A+B) + tile1 A-units; wait tile0 only ----
    stA(0, 0, 0); stA(0, 1, 0); stB(0, 0, 0); stB(0, 1, 0);
    stA(1, 0, 1); stA(1, 1, 1);
    asm volatile("s_waitcnt vmcnt(4)" ::: "memory");
    __builtin_amdgcn_s_barrier();
    __builtin_amdgcn_sched_barrier(0);

#pragma unroll
    for (int kt = 0; kt < NT; ++kt) {
        const int c = kt & 1;
        const char* bufc = smem + c * 65536;
        bf16x8 a0[4], a1[4], b0[4], b1[4];

        // ---- ph0: read A-half0 + all B; issue next-tile B staging ----
#pragma unroll
        for (int m = 0; m < 4; ++m) {
            const char* base = bufc + aRow + m * (16 * 128);
            a0[m] = *(const bf16x8*)(base + cs0);
            a1[m] = *(const bf16x8*)(base + cs1);
        }
#pragma unroll
        for (int n = 0; n < 4; ++n) {
            const char* base = bufc + bRow + n * (16 * 128);
            b0[n] = *(const bf16x8*)(base + cs0);
            b1[n] = *(const bf16x8*)(base + cs1);
        }
        if (kt + 1 < NT) { stB(c ^ 1, 0, kt + 1); stB(c ^ 1, 1, kt + 1); }
        __builtin_amdgcn_s_setprio(1);
#pragma unroll
        for (int m = 0; m < 4; ++m)
#pragma unroll
            for (int n = 0; n < 4; ++n) {
                acc[m][n] = __builtin_amdgcn_mfma_f32_16x16x32_bf16(a0[m], b0[n], acc[m][n], 0, 0, 0);
                acc[m][n] = __builtin_amdgcn_mfma_f32_16x16x32_bf16(a1[m], b1[n], acc[m][n], 0, 0, 0);
            }
        __builtin_amdgcn_s_setprio(0);

        // ---- ph1: read A-half1; free buffer; stage tile t+2 A-units ----
#pragma unroll
        for (int m = 0; m < 4; ++m) {
            const char* base = bufc + aRow + (64 + m * 16) * 128;
            a0[m] = *(const bf16x8*)(base + cs0);
            a1[m] = *(const bf16x8*)(base + cs1);
        }
        asm volatile("s_waitcnt lgkmcnt(0)" ::: "memory");
        __builtin_amdgcn_sched_barrier(0);
        if (kt + 2 < NT) {
            __builtin_amdgcn_s_barrier();          // all waves done reading buf c
            __builtin_amdgcn_sched_barrier(0);
            stA(c, 0, kt + 2); stA(c, 1, kt + 2);  // overwrite freed buffer
        }
        __builtin_amdgcn_s_setprio(1);
#pragma unroll
        for (int m = 0; m < 4; ++m)
#pragma unroll
            for (int n = 0; n < 4; ++n) {
                acc[4 + m][n] = __builtin_amdgcn_mfma_f32_16x16x32_bf16(a0[m], b0[n], acc[4 + m][n], 0, 0, 0);
                acc[4 + m][n] = __builtin_amdgcn_mfma_f32_16x16x32_bf16(a1[m], b1[n], acc[4 + m][n], 0, 0, 0);
            }
        __builtin_amdgcn_s_setprio(0);

        // ---- boundary: counted wait (tile t+1's 8 loads retired; t+2's 4 in flight) ----
        if (kt + 1 < NT) {
            if (kt + 2 < NT) { asm volatile("s_waitcnt vmcnt(4)" ::: "memory"); }
            else             { asm volatile("s_waitcnt vmcnt(0)" ::: "memory"); }
            __builtin_amdgcn_sched_barrier(0);
            __builtin_amdgcn_s_barrier();
            __builtin_amdgcn_sched_barrier(0);
        }
    }

    // ---- epilogue ----
    const int orow0 = gm + wr * 128 + lk * 4;
    const int ocol0 = gn + wc * 64 + lr;
    float bv[4];
#pragma unroll
    for (int ni = 0; ni < 4; ++ni) bv[ni] = bias[gn + wc * 64 + lr + ni * 16];
#pragma unroll
    for (int mi = 0; mi < 8; ++mi)
#pragma unroll
        for (int ni = 0; ni < 4; ++ni)
#pragma unroll
            for (int r = 0; r < 4; ++r) {
                float v = acc[mi][ni][r] + bv[ni];
                if (ACTF == 1) v = fmaxf(v, 0.f);
                long long off = (long long)(orow0 + mi * 16 + r) * ldc + ocol0 + ni * 16;
                if (OUTF == 0) Cf[off] = v;
                else           Cb[off] = f2bf(v);
            }
}

// ---------------- attention ----------------
__global__ __launch_bounds__(256) void attn_kernel(
    const float* __restrict__ query, const unsigned short* __restrict__ keys,
    const unsigned short* __restrict__ vals, unsigned short* __restrict__ tower_in,
    float* __restrict__ loss_partial)
{
    int wv   = threadIdx.x >> 6;
    int lane = threadIdx.x & 63;
    int b    = blockIdx.x * 4 + wv;
    int d0   = lane * 4;

    const float4 q4 = *(const float4*)&query[(long long)b * D + d0];

    float s[E];
#pragma unroll
    for (int e = 0; e < E; ++e) {
        uint2 kk = *(const uint2*)&keys[((long long)e * Bn + b) * D + d0];
        float k0 = __uint_as_float(kk.x << 16);
        float k1 = __uint_as_float(kk.x & 0xffff0000u);
        float k2 = __uint_as_float(kk.y << 16);
        float k3 = __uint_as_float(kk.y & 0xffff0000u);
        float p = q4.x * k0 + q4.y * k1 + q4.z * k2 + q4.w * k3;
#pragma unroll
        for (int off = 32; off > 0; off >>= 1) p += __shfl_xor(p, off, 64);
        s[e] = p;
    }

    float m = s[0];
#pragma unroll
    for (int e = 1; e < E; ++e) m = fmaxf(m, s[e]);
    float wgt[E];
    float sum = 0.f;
#pragma unroll
    for (int e = 0; e < E; ++e) { wgt[e] = expf(s[e] - m); sum += wgt[e]; }
    float inv = 1.f / sum;

    float4 acc = make_float4(0.f, 0.f, 0.f, 0.f);
    float lb = 0.f;
#pragma unroll
    for (int e = 0; e < E; ++e) {
        float we = wgt[e] * inv;
        uint2 vv = *(const uint2*)&vals[((long long)e * Bn + b) * D + d0];
        acc.x += we * __uint_as_float(vv.x << 16);
        acc.y += we * __uint_as_float(vv.x & 0xffff0000u);
        acc.z += we * __uint_as_float(vv.y << 16);
        acc.w += we * __uint_as_float(vv.y & 0xffff0000u);
        lb += fminf(fmaxf(logf(we + 1e-10f), -6.f), 0.f);
    }
    ushort4 o;
    o.x = f2bf(acc.x); o.y = f2bf(acc.y); o.z = f2bf(acc.z); o.w = f2bf(acc.w);
    *(ushort4*)&tower_in[(long long)b * D + d0] = o;

    __shared__ float sm[4];
    if (lane == 0) sm[wv] = lb;
    __syncthreads();
    if (threadIdx.x == 0)
        loss_partial[blockIdx.x] = sm[0] + sm[1] + sm[2] + sm[3];
}

// ---------------- q = t2 @ tW3 + tb3 ; block Bn/4 does loss reduce ----------------
__global__ __launch_bounds__(256) void qdot_loss_kernel(
    const float* __restrict__ t2, const float* __restrict__ tW3,
    const float* __restrict__ tb3, float* __restrict__ out,
    const float* __restrict__ lossp)
{
    if (blockIdx.x == Bn / 4) {
        float s = 0.f;
        for (int i = threadIdx.x; i < Bn / 4; i += 256) s += lossp[i];
#pragma unroll
        for (int off = 32; off > 0; off >>= 1) s += __shfl_xor(s, off, 64);
        __shared__ float sm[4];
        if ((threadIdx.x & 63) == 0) sm[threadIdx.x >> 6] = s;
        __syncthreads();
        if (threadIdx.x == 0) out[Bn] = (-0.3f / Bn) * (sm[0] + sm[1] + sm[2] + sm[3]);
        return;
    }
    int wv   = threadIdx.x >> 6;
    int lane = threadIdx.x & 63;
    int b    = blockIdx.x * 4 + wv;
    int d0   = lane * 4;
    float4 h4 = *(const float4*)&t2[(long long)b * D + d0];
    float4 w4 = *(const float4*)&tW3[d0];
    float p = h4.x * w4.x + h4.y * w4.y + h4.z * w4.z + h4.w * w4.w;
#pragma unroll
    for (int off = 32; off > 0; off >>= 1) p += __shfl_xor(p, off, 64);
    if (lane == 0) out[b] = p + tb3[0];
}

extern "C" void kernel_launch(void* const* d_in, const int* in_sizes, int n_in,
                              void* d_out, int out_size, void* d_ws, size_t ws_size,
                              hipStream_t stream) {
    const float* state_feat = (const float*)d_in[0];
    const float* act        = (const float*)d_in[1];
    const int*   task_id    = (const int*)d_in[2];
    const float* rep_W1 = (const float*)d_in[3];
    const float* rep_b1 = (const float*)d_in[4];
    const float* rep_W2 = (const float*)d_in[5];
    const float* rep_b2 = (const float*)d_in[6];
    const float* emb    = (const float*)d_in[7];
    const float* kW1 = (const float*)d_in[8];
    const float* kb1 = (const float*)d_in[9];
    const float* kW2 = (const float*)d_in[10];
    const float* kb2 = (const float*)d_in[11];
    const float* vW1 = (const float*)d_in[12];
    const float* vb1 = (const float*)d_in[13];
    const float* vW2 = (const float*)d_in[14];
    const float* vb2 = (const float*)d_in[15];
    const float* tW1 = (const float*)d_in[16];
    const float* tb1 = (const float*)d_in[17];
    const float* tW2 = (const float*)d_in[18];
    const float* tb2 = (const float*)d_in[19];
    const float* tW3 = (const float*)d_in[20];
    const float* tb3 = (const float*)d_in[21];
    float* out = (float*)d_out;

    // ---- workspace ----
    char* p = (char*)d_ws;
    auto alloc = [&](size_t bytes) {
        char* r = p;
        p += (bytes + 255) & ~(size_t)255;
        return r;
    };
    bool fused = ws_size >= (size_t)150 * 1024 * 1024;

    unsigned short* x      = (unsigned short*)alloc((size_t)Bn * KPAD * 2);
    unsigned short* repW1T = (unsigned short*)alloc((size_t)H1 * KPAD * 2);
    unsigned short* repW2T = (unsigned short*)alloc((size_t)H1 * H1 * 2);
    unsigned short* w1T    = (unsigned short*)alloc((size_t)2 * E * H2 * H1 * 2);
    unsigned short* w2T    = (unsigned short*)alloc((size_t)2 * E * D * H2 * 2);
    unsigned short* tW1T   = (unsigned short*)alloc((size_t)D * D * 2);
    unsigned short* tW2T   = (unsigned short*)alloc((size_t)D * D * 2);
    float*          b1cat  = (float*)alloc((size_t)2 * E * H2 * 4);
    float*          b2cat  = (float*)alloc((size_t)2 * E * D * 4);
    char*           h1zone = alloc((size_t)Bn * H1 * 2);
    unsigned short* rep    = (unsigned short*)alloc((size_t)Bn * H1 * 2);
    unsigned short* hkv    = (unsigned short*)alloc((size_t)(fused ? 2 * E : E) * Bn * H2 * 2);
    unsigned short* kv     = (unsigned short*)alloc((size_t)2 * E * Bn * D * 2);
    float*          query  = (float*)alloc((size_t)Bn * D * 4);
    float*          lossp  = (float*)alloc((size_t)(Bn / 4) * 4);

    unsigned short* h1       = (unsigned short*)h1zone;
    unsigned short* tower_in = (unsigned short*)h1zone;
    unsigned short* t1       = (unsigned short*)(h1zone + (size_t)Bn * D * 2);
    float*          t2       = (float*)(h1zone + (size_t)2 * Bn * D * 2);

    // ---- 1. mega transpose-cast ----
    TDescArr da;
    int startAcc = 0;
    auto setd = [&](int i, const float* W, unsigned short* WT, int K, int N, int Kpad,
                    long long gsW, long long gsO, int groups) {
        TDesc& dd = da.d[i];
        dd.W = W; dd.WT = WT; dd.K = K; dd.N = N; dd.Kpad = Kpad;
        dd.gsW = gsW; dd.gsO = gsO;
        dd.tilesX = N / 32; dd.tilesY = Kpad / 32;
        dd.perG = dd.tilesX * dd.tilesY;
        dd.start = startAcc;
        startAcc += dd.perG * groups;
    };
    setd(0, rep_W1, repW1T, IN, H1, KPAD, 0, 0, 1);
    setd(1, rep_W2, repW2T, H1, H1, H1, 0, 0, 1);
    setd(2, kW1, w1T,                       H1, H2, H1, (long long)H1 * H2, (long long)H2 * H1, E);
    setd(3, vW1, w1T + (size_t)E * H2 * H1, H1, H2, H1, (long long)H1 * H2, (long long)H2 * H1, E);
    setd(4, kW2, w2T,                       H2, D, H2, (long long)H2 * D, (long long)D * H2, E);
    setd(5, vW2, w2T + (size_t)E * D * H2,  H2, D, H2, (long long)H2 * D, (long long)D * H2, E);
    setd(6, tW1, tW1T, D, D, D, 0, 0, 1);
    setd(7, tW2, tW2T, D, D, D, 0, 0, 1);
    mega_transpose<<<startAcc, 256, 0, stream>>>(da);

    // ---- 2. bias concat + prep ----
    bias_concat<<<(2 * E * H2 + 2 * E * D) / 256, 256, 0, stream>>>(
        kb1, vb1, kb2, vb2, b1cat, b2cat);
    prep_kernel<<<(Bn * KPAD + Bn * D) / 256, 256, 0, stream>>>(
        state_feat, act, x, emb, task_id, query);

    // ---- 3. rep MLP (128^2 kernel) ----
    gemm_bf16<1, 1, 32><<<dim3(H1 / 128, Bn / 128, 1), 256, 0, stream>>>(
        x, repW1T, rep_b1, h1, KPAD, H1, 0, 0, 0, 0);
    gemm_bf16<0, 1, 64><<<dim3(H1 / 128, Bn / 128, 1), 256, 0, stream>>>(
        h1, repW2T, rep_b2, rep, H1, H1, 0, 0, 0, 0);

    // ---- 4. expert K/V MLPs (256^2 pipelined kernel) ----
    if (fused) {
        gemm256<H1, 1, 1><<<dim3(H2 / 256, Bn / 256, 2 * E), 512, 0, stream>>>(
            rep, w1T, b1cat, hkv, H2,
            0, (long long)H2 * H1, H2, (long long)Bn * H2);
        gemm256<H2, 0, 1><<<dim3(D / 256, Bn / 256, 2 * E), 512, 0, stream>>>(
            hkv, w2T, b2cat, kv, D,
            (long long)Bn * H2, (long long)D * H2, D, (long long)Bn * D);
    } else {
        for (int half = 0; half < 2; ++half) {
            gemm256<H1, 1, 1><<<dim3(H2 / 256, Bn / 256, E), 512, 0, stream>>>(
                rep, w1T + (size_t)half * E * H2 * H1, b1cat + half * E * H2, hkv, H2,
                0, (long long)H2 * H1, H2, (long long)Bn * H2);
            gemm256<H2, 0, 1><<<dim3(D / 256, Bn / 256, E), 512, 0, stream>>>(
                hkv, w2T + (size_t)half * E * D * H2, b2cat + half * E * D,
                kv + (size_t)half * E * Bn * D, D,
                (long long)Bn * H2, (long long)D * H2, D, (long long)Bn * D);
        }
    }

    // ---- 5. attention ----
    attn_kernel<<<Bn / 4, 256, 0, stream>>>(
        query, kv, kv + (size_t)E * Bn * D, tower_in, lossp);

    // ---- 6. tower (128^2 kernel) ----
    gemm_bf16<1, 1, 64><<<dim3(D / 128, Bn / 128, 1), 256, 0, stream>>>(
        tower_in, tW1T, tb1, t1, D, D, 0, 0, 0, 0);
    gemm_bf16<1, 0, 64><<<dim3(D / 128, Bn / 128, 1), 256, 0, stream>>>(
        t1, tW2T, tb2, t2, D, D, 0, 0, 0, 0);

    // ---- 7. q + loss ----
    qdot_loss_kernel<<<Bn / 4 + 1, 256, 0, stream>>>(t2, tW3, tb3, out, lossp);
}